// Round 1
// baseline (1561.099 us; speedup 1.0000x reference)
//
#include <hip/hip_runtime.h>
#include <math.h>

#define BB 256
#define DD 256
#define VV 2000
#define VT 10000
#define OPTN 16
#define SEQN 10
#define SRCN 40
#define D3 768
#define D2 512

// float32 log(1e-13f)
#define LOG_TINY (-29.9336062f)

// output offsets (floats)
#define OFF_LHS   0
#define OFF_MASK  (BB)
#define OFF_GG    (2*BB)
#define OFF_OPTS  (2*BB + BB*OPTN*4*SEQN)          // 164352
#define OFF_TOPO  (OFF_OPTS + BB*OPTN)             // 168448
#define OFF_EXACT (OFF_TOPO + 4*BB*SEQN)           // 178688

__device__ __forceinline__ float sigm(float x){ return 1.0f/(1.0f+expf(-x)); }

// gh = tree_state @ Wh + bh  (constant across steps: gru uses outer tree_state)
__global__ void k_gh(const float* __restrict__ ts0, const float* __restrict__ Wh,
                     const float* __restrict__ bh, float* __restrict__ gh){
  int b = blockIdx.x;
  int j = blockIdx.y*256 + threadIdx.x;
  __shared__ float hsh[DD];
  hsh[threadIdx.x] = ts0[b*DD + threadIdx.x];
  __syncthreads();
  float acc = bh[j];
  #pragma unroll 8
  for(int k=0;k<DD;k++) acc += hsh[k]*Wh[k*D3 + j];
  gh[b*D3 + j] = acc;
}

// fused per-step: x=emb[inp]; gru; attention; soa=tanh([ctx,h]@Wc+bc); ts update
__global__ void k_step(const int* __restrict__ inp, const float* __restrict__ emb,
                       const float* __restrict__ ts0, const float* __restrict__ gh,
                       const float* __restrict__ Wx, const float* __restrict__ bx,
                       const float* __restrict__ mem, const float* __restrict__ Wc,
                       const float* __restrict__ bc, float* __restrict__ soa,
                       float* __restrict__ ts){
  int b = blockIdx.x, tid = threadIdx.x;
  __shared__ float xs[DD], hs[DD], cs[DD], sc[SRCN];
  int sym = inp[b];
  xs[tid] = emb[sym*DD + tid];
  __syncthreads();
  float a0 = bx[tid], a1 = bx[256+tid], a2 = bx[512+tid];
  #pragma unroll 4
  for(int k=0;k<DD;k++){
    float xv = xs[k];
    const float* w = Wx + k*D3;
    a0 = fmaf(xv, w[tid],     a0);
    a1 = fmaf(xv, w[256+tid], a1);
    a2 = fmaf(xv, w[512+tid], a2);
  }
  float r = sigm(a0 + gh[b*D3 + tid]);
  float z = sigm(a1 + gh[b*D3 + 256 + tid]);
  float n = tanhf(a2 + r*gh[b*D3 + 512 + tid]);
  float h = (1.0f - z)*n + z*ts0[b*DD + tid];
  hs[tid] = h;
  __syncthreads();
  // attention scores: 4 waves x 10 scores, dot over D
  int lane = tid & 63, wv = tid >> 6;
  for(int s = wv; s < SRCN; s += 4){
    float p = 0.f;
    const float* mrow = mem + (size_t)(b*SRCN + s)*DD;
    #pragma unroll 4
    for(int d = lane; d < DD; d += 64) p = fmaf(hs[d], mrow[d], p);
    for(int off=32; off; off>>=1) p += __shfl_down(p, off, 64);
    if(lane==0) sc[s] = p;
  }
  __syncthreads();
  if(tid==0){
    float mx = sc[0];
    for(int s=1;s<SRCN;s++) mx = fmaxf(mx, sc[s]);
    float sum = 0.f;
    for(int s=0;s<SRCN;s++){ float e = expf(sc[s]-mx); sc[s]=e; sum+=e; }
    float inv = 1.0f/sum;
    for(int s=0;s<SRCN;s++) sc[s]*=inv;
  }
  __syncthreads();
  float c = 0.f;
  #pragma unroll 8
  for(int s=0;s<SRCN;s++) c = fmaf(sc[s], mem[(size_t)(b*SRCN+s)*DD + tid], c);
  cs[tid] = c;
  __syncthreads();
  float acc = bc[tid];
  #pragma unroll 4
  for(int k=0;k<DD;k++) acc = fmaf(cs[k], Wc[k*DD + tid], acc);
  #pragma unroll 4
  for(int k=0;k<DD;k++) acc = fmaf(hs[k], Wc[(k+DD)*DD + tid], acc);
  float sv = tanhf(acc);
  soa[b*DD + tid] = sv;
  ts[b*DD + tid] = tanhf(ts[b*DD + tid] + sv);
}

// clogits[t][b][v] = soa[b]@Wsym[:,v] + bsym[v] + (allowed? 0 : LOG_TINY)
// tiled 64x64, K=256, block 256 threads (16x16), 4x4 micro
__global__ void k_clogits(const float* __restrict__ A, const float* __restrict__ Wsym,
                          const float* __restrict__ bsym, const int* __restrict__ gg,
                          int t, float* __restrict__ cl){
  __shared__ float As[16][64];
  __shared__ float Bs[16][64];
  __shared__ int sel[64][OPTN];
  int tid = threadIdx.x;
  int tx = tid & 15, ty = tid >> 4;
  int m0 = blockIdx.y*64, n0 = blockIdx.x*64;
  for(int idx = tid; idx < 64*OPTN; idx += 256){
    int i = idx >> 4, o = idx & 15;
    int bb = m0 + i;
    int base = ((bb*OPTN + o)*4)*SEQN + t;
    int mk = gg[base + 3*SEQN];
    sel[i][o] = mk ? gg[base] : -1;
  }
  float acc[4][4];
  #pragma unroll
  for(int i=0;i<4;i++){ acc[i][0]=0.f; acc[i][1]=0.f; acc[i][2]=0.f; acc[i][3]=0.f; }
  for(int k0=0;k0<DD;k0+=16){
    {
      int row = tid >> 2, kk = (tid & 3)*4;
      float4 av = *(const float4*)&A[(m0+row)*DD + k0 + kk];
      As[kk+0][row]=av.x; As[kk+1][row]=av.y; As[kk+2][row]=av.z; As[kk+3][row]=av.w;
    }
    {
      int r = tid >> 4, c2 = (tid & 15)*4;
      int n = n0 + c2;
      float4 bv;
      if(n + 3 < VV){ bv = *(const float4*)&Wsym[(k0+r)*VV + n]; }
      else {
        bv.x = (n+0<VV)? Wsym[(k0+r)*VV + n+0] : 0.f;
        bv.y = (n+1<VV)? Wsym[(k0+r)*VV + n+1] : 0.f;
        bv.z = (n+2<VV)? Wsym[(k0+r)*VV + n+2] : 0.f;
        bv.w = (n+3<VV)? Wsym[(k0+r)*VV + n+3] : 0.f;
      }
      *(float4*)&Bs[r][c2] = bv;
    }
    __syncthreads();
    #pragma unroll
    for(int k=0;k<16;k++){
      float4 a4 = *(const float4*)&As[k][ty*4];
      float4 b4 = *(const float4*)&Bs[k][tx*4];
      float av[4] = {a4.x,a4.y,a4.z,a4.w};
      float bw[4] = {b4.x,b4.y,b4.z,b4.w};
      #pragma unroll
      for(int i=0;i<4;i++)
        #pragma unroll
        for(int j=0;j<4;j++) acc[i][j] = fmaf(av[i], bw[j], acc[i][j]);
    }
    __syncthreads();
  }
  #pragma unroll
  for(int i=0;i<4;i++){
    int m = m0 + ty*4 + i;
    #pragma unroll
    for(int j=0;j<4;j++){
      int n = n0 + tx*4 + j;
      if(n < VV){
        bool allowed = false;
        #pragma unroll
        for(int o=0;o<OPTN;o++) allowed |= (sel[ty*4+i][o] == n);
        cl[((size_t)t*BB + m)*VV + n] = acc[i][j] + bsym[n] + (allowed? 0.f : LOG_TINY);
      }
    }
  }
}

// per (t,b): argmax over V (first occurrence) -> inp; logsumexp -> lse
__global__ void k_reduce(const float* __restrict__ cl, int t, float* __restrict__ lse,
                         int* __restrict__ inp){
  int b = blockIdx.x, tid = threadIdx.x;
  const float* row = cl + ((size_t)t*BB + b)*VV;
  float mx = -1e30f; int mi = 0;
  for(int v=tid; v<VV; v+=256){
    float val = row[v];
    if(val > mx){ mx = val; mi = v; }
  }
  __shared__ float smx[256]; __shared__ int smi[256]; __shared__ float ssum[256];
  smx[tid]=mx; smi[tid]=mi; __syncthreads();
  for(int s=128; s; s>>=1){
    if(tid < s){
      if(smx[tid+s] > smx[tid] || (smx[tid+s]==smx[tid] && smi[tid+s] < smi[tid])){
        smx[tid]=smx[tid+s]; smi[tid]=smi[tid+s];
      }
    }
    __syncthreads();
  }
  float gmx = smx[0];
  float sum = 0.f;
  for(int v=tid; v<VV; v+=256) sum += expf(row[v]-gmx);
  ssum[tid]=sum; __syncthreads();
  for(int s=128; s; s>>=1){ if(tid<s) ssum[tid]+=ssum[tid+s]; __syncthreads(); }
  if(tid==0){ lse[t*BB + b] = gmx + logf(ssum[0]); inp[b] = smi[0]; }
}

// opts_logp, best, topo outputs, sym_i
__global__ void k_opts(const float* __restrict__ cl, const float* __restrict__ lse,
                       const int* __restrict__ gg, float* __restrict__ out,
                       int* __restrict__ sym_i){
  int b = blockIdx.x, tid = threadIdx.x;  // 64 threads
  __shared__ float sacc[OPTN];
  __shared__ int sbest;
  if(tid < OPTN){
    int o = tid;
    float acc = 0.f;
    for(int t=0;t<SEQN;t++){
      int base = ((b*OPTN + o)*4)*SEQN + t;
      int mk = gg[base + 3*SEQN];
      if(mk){
        int v = gg[base];
        float p = expf(cl[((size_t)t*BB + b)*VV + v] - lse[t*BB + b]);
        acc += logf(p + 1e-13f);
      }
    }
    sacc[o] = acc;
    out[OFF_OPTS + b*OPTN + o] = acc;
  }
  __syncthreads();
  if(tid==0){
    float mx = sacc[0]; int mi = 0;
    for(int o=1;o<OPTN;o++) if(sacc[o] > mx){ mx = sacc[o]; mi = o; }
    sbest = mi;
  }
  __syncthreads();
  if(tid < 4*SEQN){
    int c = tid/SEQN, t = tid%SEQN;
    int val = gg[((b*OPTN + sbest)*4 + c)*SEQN + t];
    out[OFF_TOPO + c*(BB*SEQN) + b*SEQN + t] = (float)val;
    if(c==0) sym_i[b*SEQN + t] = val;
  }
}

// passthrough outputs 0..2 as float
__global__ void k_pass(const int* __restrict__ lhs, const int* __restrict__ lhs_mask,
                       const int* __restrict__ gg, float* __restrict__ out){
  int i = blockIdx.x*256 + threadIdx.x;
  if(i < BB) out[i] = (float)lhs[i];
  else if(i < 2*BB) out[i] = (float)lhs_mask[i - BB];
  else if(i < 2*BB + BB*OPTN*4*SEQN) out[OFF_GG + (i - 2*BB)] = (float)gg[i - 2*BB];
}

// exact_logit: M=2560 x N=10000, K=512 fp32 tiled GEMM + epilogue
__global__ void k_tok(const int* __restrict__ sym_i, const float* __restrict__ emb,
                      const float* __restrict__ tsf, const float* __restrict__ Wtok,
                      const float* __restrict__ btok, const float* __restrict__ tok_table,
                      float* __restrict__ out){
  __shared__ float As[16][64];
  __shared__ float Bs[16][64];
  int tid = threadIdx.x;
  int tx = tid & 15, ty = tid >> 4;
  int m0 = blockIdx.y*64, n0 = blockIdx.x*64;
  float acc[4][4];
  #pragma unroll
  for(int i=0;i<4;i++){ acc[i][0]=0.f; acc[i][1]=0.f; acc[i][2]=0.f; acc[i][3]=0.f; }
  for(int k0=0;k0<D2;k0+=16){
    {
      int row = tid >> 2, kk = (tid & 3)*4;
      int m = m0 + row;
      float4 av;
      if(k0 < DD){
        int s = sym_i[m];
        av = *(const float4*)&emb[s*DD + k0 + kk];
      } else {
        int bb = m/SEQN;
        av = *(const float4*)&tsf[bb*DD + (k0 - DD) + kk];
      }
      As[kk+0][row]=av.x; As[kk+1][row]=av.y; As[kk+2][row]=av.z; As[kk+3][row]=av.w;
    }
    {
      int r = tid >> 4, c2 = (tid & 15)*4;
      int n = n0 + c2;
      float4 bv;
      if(n + 3 < VT){ bv = *(const float4*)&Wtok[(size_t)(k0+r)*VT + n]; }
      else {
        const float* src = Wtok + (size_t)(k0+r)*VT;
        bv.x = (n+0<VT)? src[n+0] : 0.f;
        bv.y = (n+1<VT)? src[n+1] : 0.f;
        bv.z = (n+2<VT)? src[n+2] : 0.f;
        bv.w = (n+3<VT)? src[n+3] : 0.f;
      }
      *(float4*)&Bs[r][c2] = bv;
    }
    __syncthreads();
    #pragma unroll
    for(int k=0;k<16;k++){
      float4 a4 = *(const float4*)&As[k][ty*4];
      float4 b4 = *(const float4*)&Bs[k][tx*4];
      float av[4] = {a4.x,a4.y,a4.z,a4.w};
      float bw[4] = {b4.x,b4.y,b4.z,b4.w};
      #pragma unroll
      for(int i=0;i<4;i++)
        #pragma unroll
        for(int j=0;j<4;j++) acc[i][j] = fmaf(av[i], bw[j], acc[i][j]);
    }
    __syncthreads();
  }
  #pragma unroll
  for(int i=0;i<4;i++){
    int m = m0 + ty*4 + i;
    int s = sym_i[m];
    const float* tt = tok_table + (size_t)s*VT;
    #pragma unroll
    for(int j=0;j<4;j++){
      int n = n0 + tx*4 + j;
      if(n < VT)
        out[OFF_EXACT + (size_t)m*VT + n] = acc[i][j] + btok[n] + logf(tt[n] + 1e-13f);
    }
  }
}

extern "C" void kernel_launch(void* const* d_in, const int* in_sizes, int n_in,
                              void* d_out, int out_size, void* d_ws, size_t ws_size,
                              hipStream_t stream) {
  const int*   lhs       = (const int*)  d_in[0];
  const int*   lhs_mask  = (const int*)  d_in[1];
  const float* tree_state= (const float*)d_in[2];
  const int*   gg        = (const int*)  d_in[3];
  const float* emb       = (const float*)d_in[4];
  const float* mem       = (const float*)d_in[5];
  const float* Wx        = (const float*)d_in[6];
  const float* Wh        = (const float*)d_in[7];
  const float* bx        = (const float*)d_in[8];
  const float* bh        = (const float*)d_in[9];
  const float* Wc        = (const float*)d_in[10];
  const float* bc        = (const float*)d_in[11];
  const float* Wsym      = (const float*)d_in[12];
  const float* bsym      = (const float*)d_in[13];
  const float* Wtok      = (const float*)d_in[14];
  const float* btok      = (const float*)d_in[15];
  const float* tok_table = (const float*)d_in[16];
  float* out = (float*)d_out;

  float* W    = (float*)d_ws;
  float* gh   = W;                       // B*768
  float* ts   = gh  + BB*D3;             // B*256
  float* soa  = ts  + BB*DD;             // B*256
  float* cl   = soa + BB*DD;             // SEQ*B*V = 5,120,000
  float* lse  = cl  + (size_t)SEQN*BB*VV;// SEQ*B
  int*   inp  = (int*)(lse + SEQN*BB);   // B
  int*   sym_i= inp + BB;                // B*SEQ

  hipMemcpyAsync(ts,  tree_state, BB*DD*sizeof(float), hipMemcpyDeviceToDevice, stream);
  hipMemcpyAsync(inp, lhs,        BB*sizeof(int),      hipMemcpyDeviceToDevice, stream);

  k_gh<<<dim3(BB,3), 256, 0, stream>>>(tree_state, Wh, bh, gh);

  for(int t=0; t<SEQN; t++){
    k_step<<<BB, 256, 0, stream>>>(inp, emb, tree_state, gh, Wx, bx, mem, Wc, bc, soa, ts);
    k_clogits<<<dim3(32,4), 256, 0, stream>>>(soa, Wsym, bsym, gg, t, cl);
    k_reduce<<<BB, 256, 0, stream>>>(cl, t, lse, inp);
  }

  k_opts<<<BB, 64, 0, stream>>>(cl, lse, gg, out, sym_i);
  k_pass<<<(2*BB + BB*OPTN*4*SEQN + 255)/256, 256, 0, stream>>>(lhs, lhs_mask, gg, out);
  k_tok<<<dim3((VT+63)/64, (BB*SEQN)/64), 256, 0, stream>>>(sym_i, emb, ts, Wtok, btok, tok_table, out);
}

// Round 2
// 1104.508 us; speedup vs baseline: 1.4134x; 1.4134x over previous
//
#include <hip/hip_runtime.h>
#include <math.h>

#define BB 256
#define DD 256
#define VV 2000
#define VT 10000
#define OPTN 16
#define SEQN 10
#define SRCN 40
#define D3 768
#define D2 512

#define LOG_TINY (-29.9336062f)

// output offsets (floats)
#define OFF_OPTS  (2*BB + BB*OPTN*4*SEQN)          // 164352
#define OFF_TOPO  (OFF_OPTS + BB*OPTN)             // 168448
#define OFF_EXACT (OFF_TOPO + 4*BB*SEQN)           // 178688

typedef __bf16 bf16x8 __attribute__((ext_vector_type(8)));
typedef float  f32x4  __attribute__((ext_vector_type(4)));

__device__ __forceinline__ float sigm(float x){ return 1.0f/(1.0f+expf(-x)); }
__device__ __forceinline__ unsigned short f2bf(float x){
  union { float f; unsigned int u; } v; v.f = x;
  unsigned int r = (v.u + 0x7FFF + ((v.u >> 16) & 1)) >> 16;
  return (unsigned short)r;
}

// gh = tree_state @ Wh + bh  (constant across steps: gru uses outer tree_state)
__global__ void k_gh(const float* __restrict__ ts0, const float* __restrict__ Wh,
                     const float* __restrict__ bh, float* __restrict__ gh){
  int b = blockIdx.x;
  int j = blockIdx.y*256 + threadIdx.x;
  __shared__ float hsh[DD];
  hsh[threadIdx.x] = ts0[b*DD + threadIdx.x];
  __syncthreads();
  float acc = bh[j];
  #pragma unroll 8
  for(int k=0;k<DD;k++) acc += hsh[k]*Wh[k*D3 + j];
  gh[b*D3 + j] = acc;
}

// EW = emb @ Wx  (2000 x 768, K=256) fp32 64x64 tiler
__global__ void k_ew(const float* __restrict__ emb, const float* __restrict__ Wx,
                     float* __restrict__ EW){
  __shared__ float As[16][64];
  __shared__ float Bs[16][64];
  int tid = threadIdx.x;
  int tx = tid & 15, ty = tid >> 4;
  int m0 = blockIdx.y*64, n0 = blockIdx.x*64;
  float acc[4][4];
  #pragma unroll
  for(int i=0;i<4;i++){ acc[i][0]=0.f; acc[i][1]=0.f; acc[i][2]=0.f; acc[i][3]=0.f; }
  for(int k0=0;k0<DD;k0+=16){
    {
      int row = tid >> 2, kk = (tid & 3)*4;
      int m = m0 + row;
      float4 av = {0,0,0,0};
      if(m < VV) av = *(const float4*)&emb[m*DD + k0 + kk];
      As[kk+0][row]=av.x; As[kk+1][row]=av.y; As[kk+2][row]=av.z; As[kk+3][row]=av.w;
    }
    {
      int r = tid >> 4, c2 = (tid & 15)*4;
      float4 bv = *(const float4*)&Wx[(k0+r)*D3 + n0 + c2];
      *(float4*)&Bs[r][c2] = bv;
    }
    __syncthreads();
    #pragma unroll
    for(int k=0;k<16;k++){
      float4 a4 = *(const float4*)&As[k][ty*4];
      float4 b4 = *(const float4*)&Bs[k][tx*4];
      float av[4] = {a4.x,a4.y,a4.z,a4.w};
      float bw[4] = {b4.x,b4.y,b4.z,b4.w};
      #pragma unroll
      for(int i=0;i<4;i++)
        #pragma unroll
        for(int j=0;j<4;j++) acc[i][j] = fmaf(av[i], bw[j], acc[i][j]);
    }
    __syncthreads();
  }
  #pragma unroll
  for(int i=0;i<4;i++){
    int m = m0 + ty*4 + i;
    if(m < VV){
      #pragma unroll
      for(int j=0;j<4;j++) EW[m*D3 + n0 + tx*4 + j] = acc[i][j];
    }
  }
}

// Wtok [512][10000] fp32 -> WtokB [10000][512] bf16 (transpose + convert)
__global__ void k_wtokT(const float* __restrict__ Wtok, unsigned short* __restrict__ WtokB){
  __shared__ float tile[32][65];
  int tid = threadIdx.x;
  int n0 = blockIdx.x*64, k0 = blockIdx.y*32;
  #pragma unroll
  for(int p=0;p<8;p++){
    int idx = tid + p*256;
    int kk = idx >> 6, nn = idx & 63;
    int n = n0 + nn;
    tile[kk][nn] = (n < VT) ? Wtok[(size_t)(k0+kk)*VT + n] : 0.f;
  }
  __syncthreads();
  #pragma unroll
  for(int p=0;p<4;p++){
    int idx = tid + p*256;
    int nn = idx >> 4, kk = (idx & 15)*2;
    int n = n0 + nn;
    if(n < VT){
      ushort2 v;
      v.x = f2bf(tile[kk][nn]);
      v.y = f2bf(tile[kk+1][nn]);
      *(ushort2*)&WtokB[(size_t)n*D2 + k0 + kk] = v;
    }
  }
}

// fused per-step: argmax(cl[t-1]) -> sym; gates from EW gather; gru; attention;
// soa=tanh([ctx,h]@Wc+bc); ts update
__global__ void k_step(const float* __restrict__ cl_prev, const int* __restrict__ lhs,
                       const float* __restrict__ EW, const float* __restrict__ gh,
                       const float* __restrict__ bx, const float* __restrict__ ts0,
                       const float* __restrict__ mem, const float* __restrict__ Wc,
                       const float* __restrict__ bc, float* __restrict__ soa,
                       float* __restrict__ ts){
  int b = blockIdx.x, tid = threadIdx.x;
  __shared__ float hs[DD], cs[DD], sc[SRCN];
  __shared__ float smx[256]; __shared__ int smi[256];
  __shared__ int sym_sh;
  int sym;
  if(cl_prev){
    const float* row = cl_prev + (size_t)b*VV;
    float mx = -1e30f; int mi = 0;
    for(int v=tid; v<VV; v+=256){
      float val = row[v];
      if(val > mx){ mx = val; mi = v; }
    }
    smx[tid]=mx; smi[tid]=mi; __syncthreads();
    for(int s=128; s; s>>=1){
      if(tid < s){
        if(smx[tid+s] > smx[tid] || (smx[tid+s]==smx[tid] && smi[tid+s] < smi[tid])){
          smx[tid]=smx[tid+s]; smi[tid]=smi[tid+s];
        }
      }
      __syncthreads();
    }
    if(tid==0) sym_sh = smi[0];
    __syncthreads();
    sym = sym_sh;
  } else {
    sym = lhs[b];
  }
  const float* ew = EW + sym*D3;
  const float* ghb = gh + b*D3;
  float r = sigm(ew[tid]     + bx[tid]     + ghb[tid]);
  float z = sigm(ew[256+tid] + bx[256+tid] + ghb[256+tid]);
  float n = tanhf(ew[512+tid] + bx[512+tid] + r*ghb[512+tid]);
  float h = (1.0f - z)*n + z*ts0[b*DD + tid];
  hs[tid] = h;
  __syncthreads();
  int lane = tid & 63, wv = tid >> 6;
  for(int s = wv; s < SRCN; s += 4){
    float p = 0.f;
    const float* mrow = mem + (size_t)(b*SRCN + s)*DD;
    #pragma unroll 4
    for(int d = lane; d < DD; d += 64) p = fmaf(hs[d], mrow[d], p);
    for(int off=32; off; off>>=1) p += __shfl_down(p, off, 64);
    if(lane==0) sc[s] = p;
  }
  __syncthreads();
  if(tid==0){
    float mx = sc[0];
    for(int s=1;s<SRCN;s++) mx = fmaxf(mx, sc[s]);
    float sum = 0.f;
    for(int s=0;s<SRCN;s++){ float e = expf(sc[s]-mx); sc[s]=e; sum+=e; }
    float inv = 1.0f/sum;
    for(int s=0;s<SRCN;s++) sc[s]*=inv;
  }
  __syncthreads();
  float c = 0.f;
  #pragma unroll 8
  for(int s=0;s<SRCN;s++) c = fmaf(sc[s], mem[(size_t)(b*SRCN+s)*DD + tid], c);
  cs[tid] = c;
  __syncthreads();
  float acc = bc[tid];
  #pragma unroll 4
  for(int k=0;k<DD;k++) acc = fmaf(cs[k], Wc[k*DD + tid], acc);
  #pragma unroll 4
  for(int k=0;k<DD;k++) acc = fmaf(hs[k], Wc[(k+DD)*DD + tid], acc);
  float sv = tanhf(acc);
  soa[b*DD + tid] = sv;
  ts[b*DD + tid] = tanhf(ts[b*DD + tid] + sv);
}

// clogits[t][b][v] = soa[b]@Wsym[:,v] + bsym[v] + (allowed? 0 : LOG_TINY)
__global__ void k_clogits(const float* __restrict__ A, const float* __restrict__ Wsym,
                          const float* __restrict__ bsym, const int* __restrict__ gg,
                          int t, float* __restrict__ cl){
  __shared__ float As[16][64];
  __shared__ float Bs[16][64];
  __shared__ int sel[64][OPTN];
  int tid = threadIdx.x;
  int tx = tid & 15, ty = tid >> 4;
  int m0 = blockIdx.y*64, n0 = blockIdx.x*64;
  for(int idx = tid; idx < 64*OPTN; idx += 256){
    int i = idx >> 4, o = idx & 15;
    int bb = m0 + i;
    int base = ((bb*OPTN + o)*4)*SEQN + t;
    int mk = gg[base + 3*SEQN];
    sel[i][o] = mk ? gg[base] : -1;
  }
  float acc[4][4];
  #pragma unroll
  for(int i=0;i<4;i++){ acc[i][0]=0.f; acc[i][1]=0.f; acc[i][2]=0.f; acc[i][3]=0.f; }
  for(int k0=0;k0<DD;k0+=16){
    {
      int row = tid >> 2, kk = (tid & 3)*4;
      float4 av = *(const float4*)&A[(m0+row)*DD + k0 + kk];
      As[kk+0][row]=av.x; As[kk+1][row]=av.y; As[kk+2][row]=av.z; As[kk+3][row]=av.w;
    }
    {
      int r = tid >> 4, c2 = (tid & 15)*4;
      int n = n0 + c2;
      float4 bv;
      if(n + 3 < VV){ bv = *(const float4*)&Wsym[(k0+r)*VV + n]; }
      else {
        bv.x = (n+0<VV)? Wsym[(k0+r)*VV + n+0] : 0.f;
        bv.y = (n+1<VV)? Wsym[(k0+r)*VV + n+1] : 0.f;
        bv.z = (n+2<VV)? Wsym[(k0+r)*VV + n+2] : 0.f;
        bv.w = (n+3<VV)? Wsym[(k0+r)*VV + n+3] : 0.f;
      }
      *(float4*)&Bs[r][c2] = bv;
    }
    __syncthreads();
    #pragma unroll
    for(int k=0;k<16;k++){
      float4 a4 = *(const float4*)&As[k][ty*4];
      float4 b4 = *(const float4*)&Bs[k][tx*4];
      float av[4] = {a4.x,a4.y,a4.z,a4.w};
      float bw[4] = {b4.x,b4.y,b4.z,b4.w};
      #pragma unroll
      for(int i=0;i<4;i++)
        #pragma unroll
        for(int j=0;j<4;j++) acc[i][j] = fmaf(av[i], bw[j], acc[i][j]);
    }
    __syncthreads();
  }
  #pragma unroll
  for(int i=0;i<4;i++){
    int m = m0 + ty*4 + i;
    #pragma unroll
    for(int j=0;j<4;j++){
      int n = n0 + tx*4 + j;
      if(n < VV){
        bool allowed = false;
        #pragma unroll
        for(int o=0;o<OPTN;o++) allowed |= (sel[ty*4+i][o] == n);
        cl[((size_t)t*BB + m)*VV + n] = acc[i][j] + bsym[n] + (allowed? 0.f : LOG_TINY);
      }
    }
  }
}

// per-b: lse for all t; opts_logp; best; topo outputs; sym_i; build bf16 A rows
__global__ void k_opts(const float* __restrict__ cl, const int* __restrict__ gg,
                       const float* __restrict__ emb, const float* __restrict__ ts,
                       float* __restrict__ out, int* __restrict__ sym_i,
                       unsigned short* __restrict__ A){
  int b = blockIdx.x, tid = threadIdx.x;
  __shared__ float red[256];
  __shared__ float lse_sh[SEQN];
  __shared__ float sacc[OPTN];
  __shared__ int ssym[SEQN];
  __shared__ int sbest;
  for(int t=0;t<SEQN;t++){
    const float* row = cl + ((size_t)t*BB + b)*VV;
    float mx = -1e30f;
    for(int v=tid; v<VV; v+=256) mx = fmaxf(mx, row[v]);
    red[tid]=mx; __syncthreads();
    for(int s=128;s;s>>=1){ if(tid<s) red[tid]=fmaxf(red[tid],red[tid+s]); __syncthreads(); }
    float gmx = red[0]; __syncthreads();
    float sum = 0.f;
    for(int v=tid; v<VV; v+=256) sum += expf(row[v]-gmx);
    red[tid]=sum; __syncthreads();
    for(int s=128;s;s>>=1){ if(tid<s) red[tid]+=red[tid+s]; __syncthreads(); }
    if(tid==0) lse_sh[t] = gmx + logf(red[0]);
    __syncthreads();
  }
  if(tid < OPTN){
    int o = tid;
    float acc = 0.f;
    for(int t=0;t<SEQN;t++){
      int base = ((b*OPTN + o)*4)*SEQN + t;
      int mk = gg[base + 3*SEQN];
      if(mk){
        int v = gg[base];
        float p = expf(cl[((size_t)t*BB + b)*VV + v] - lse_sh[t]);
        acc += logf(p + 1e-13f);
      }
    }
    sacc[o] = acc;
    out[OFF_OPTS + b*OPTN + o] = acc;
  }
  __syncthreads();
  if(tid==0){
    float mx = sacc[0]; int mi = 0;
    for(int o=1;o<OPTN;o++) if(sacc[o] > mx){ mx = sacc[o]; mi = o; }
    sbest = mi;
  }
  __syncthreads();
  if(tid < 4*SEQN){
    int c = tid/SEQN, t = tid%SEQN;
    int val = gg[((b*OPTN + sbest)*4 + c)*SEQN + t];
    out[OFF_TOPO + c*(BB*SEQN) + b*SEQN + t] = (float)val;
    if(c==0){ sym_i[b*SEQN + t] = val; ssym[t] = val; }
  }
  __syncthreads();
  // build A rows m=b*10+t : [emb[sym] | ts[b]] as bf16
  for(int idx = tid; idx < SEQN*D2; idx += 256){
    int t = idx >> 9, k = idx & 511;
    float val = (k < DD) ? emb[ssym[t]*DD + k] : ts[b*DD + (k-DD)];
    A[(size_t)(b*SEQN + t)*D2 + k] = f2bf(val);
  }
}

// passthrough outputs 0..2 as float
__global__ void k_pass(const int* __restrict__ lhs, const int* __restrict__ lhs_mask,
                       const int* __restrict__ gg, float* __restrict__ out){
  int i = blockIdx.x*256 + threadIdx.x;
  if(i < BB) out[i] = (float)lhs[i];
  else if(i < 2*BB) out[i] = (float)lhs_mask[i - BB];
  else if(i < 2*BB + BB*OPTN*4*SEQN) out[2*BB + (i - 2*BB)] = (float)gg[i - 2*BB];
}

// exact_logit: bf16 MFMA GEMM, M=2560 x N=10000, K=512, 128x128 tiles
__global__ __launch_bounds__(256) void k_tok_mfma(
    const unsigned short* __restrict__ A, const unsigned short* __restrict__ Bw,
    const float* __restrict__ btok, const float* __restrict__ tok_table,
    const int* __restrict__ sym_i, float* __restrict__ out){
  __shared__ unsigned short As[128*40];
  __shared__ unsigned short Bs[128*40];
  int tid = threadIdx.x;
  int lane = tid & 63, wave = tid >> 6;
  int c = lane & 15, q = lane >> 4;
  int wm = (wave >> 1)*64, wn = (wave & 1)*64;
  int m0 = blockIdx.y*128, n0 = blockIdx.x*128;
  f32x4 acc[4][4];
  #pragma unroll
  for(int i=0;i<4;i++)
    #pragma unroll
    for(int j=0;j<4;j++) acc[i][j] = (f32x4){0.f,0.f,0.f,0.f};

  for(int k0=0;k0<D2;k0+=32){
    #pragma unroll
    for(int ci = tid; ci < 512; ci += 256){
      int row = ci >> 2, ko = (ci & 3)*8;
      float4 av = *(const float4*)(A + (size_t)(m0+row)*D2 + k0 + ko);
      *(float4*)(As + row*40 + ko) = av;
      int n = n0 + row;
      float4 bv = {0,0,0,0};
      if(n < VT) bv = *(const float4*)(Bw + (size_t)n*D2 + k0 + ko);
      *(float4*)(Bs + row*40 + ko) = bv;
    }
    __syncthreads();
    bf16x8 af[4], bf[4];
    #pragma unroll
    for(int i=0;i<4;i++) af[i] = *(const bf16x8*)(As + (wm + i*16 + c)*40 + q*8);
    #pragma unroll
    for(int j=0;j<4;j++) bf[j] = *(const bf16x8*)(Bs + (wn + j*16 + c)*40 + q*8);
    #pragma unroll
    for(int i=0;i<4;i++)
      #pragma unroll
      for(int j=0;j<4;j++)
        acc[i][j] = __builtin_amdgcn_mfma_f32_16x16x32_bf16(af[i], bf[j], acc[i][j], 0, 0, 0);
    __syncthreads();
  }
  #pragma unroll
  for(int i=0;i<4;i++){
    #pragma unroll
    for(int r=0;r<4;r++){
      int m = m0 + wm + i*16 + q*4 + r;
      int s = sym_i[m];
      const float* tt = tok_table + (size_t)s*VT;
      #pragma unroll
      for(int j=0;j<4;j++){
        int n = n0 + wn + j*16 + c;
        if(n < VT)
          out[OFF_EXACT + (size_t)m*VT + n] = acc[i][j][r] + btok[n] + logf(tt[n] + 1e-13f);
      }
    }
  }
}

extern "C" void kernel_launch(void* const* d_in, const int* in_sizes, int n_in,
                              void* d_out, int out_size, void* d_ws, size_t ws_size,
                              hipStream_t stream) {
  const int*   lhs       = (const int*)  d_in[0];
  const int*   lhs_mask  = (const int*)  d_in[1];
  const float* tree_state= (const float*)d_in[2];
  const int*   gg        = (const int*)  d_in[3];
  const float* emb       = (const float*)d_in[4];
  const float* mem       = (const float*)d_in[5];
  const float* Wx        = (const float*)d_in[6];
  const float* Wh        = (const float*)d_in[7];
  const float* bx        = (const float*)d_in[8];
  const float* bh        = (const float*)d_in[9];
  const float* Wc        = (const float*)d_in[10];
  const float* bc        = (const float*)d_in[11];
  const float* Wsym      = (const float*)d_in[12];
  const float* bsym      = (const float*)d_in[13];
  const float* Wtok      = (const float*)d_in[14];
  const float* btok      = (const float*)d_in[15];
  const float* tok_table = (const float*)d_in[16];
  float* out = (float*)d_out;

  float* W    = (float*)d_ws;
  float* gh   = W;                        // 196608
  float* ts   = gh  + BB*D3;              // 65536
  float* soa  = ts  + BB*DD;              // 65536
  float* cl   = soa + BB*DD;              // 5,120,000
  float* EW   = cl  + (size_t)SEQN*BB*VV; // 1,536,000
  int*   sym_i= (int*)(EW + VV*D3);       // 2560
  unsigned short* Abf  = (unsigned short*)(sym_i + BB*SEQN);  // 2560*512
  unsigned short* WtokB= Abf + (size_t)BB*SEQN*D2;            // 10000*512

  hipMemcpyAsync(ts, tree_state, BB*DD*sizeof(float), hipMemcpyDeviceToDevice, stream);

  k_pass<<<(2*BB + BB*OPTN*4*SEQN + 255)/256, 256, 0, stream>>>(lhs, lhs_mask, gg, out);
  k_wtokT<<<dim3((VT+63)/64, D2/32), 256, 0, stream>>>(Wtok, WtokB);
  k_gh<<<dim3(BB,3), 256, 0, stream>>>(tree_state, Wh, bh, gh);
  k_ew<<<dim3(D3/64, (VV+63)/64), 256, 0, stream>>>(emb, Wx, EW);

  for(int t=0; t<SEQN; t++){
    const float* cl_prev = (t == 0) ? nullptr : (cl + (size_t)(t-1)*BB*VV);
    k_step<<<BB, 256, 0, stream>>>(cl_prev, lhs, EW, gh, bx, tree_state, mem, Wc, bc, soa, ts);
    k_clogits<<<dim3(32,4), 256, 0, stream>>>(soa, Wsym, bsym, gg, t, cl);
  }

  k_opts<<<BB, 256, 0, stream>>>(cl, gg, emb, ts, out, sym_i, Abf);
  k_tok_mfma<<<dim3((VT+127)/128, (BB*SEQN)/128), 256, 0, stream>>>(Abf, WtokB, btok, tok_table, sym_i, out);
}